// Round 2
// baseline (386.461 us; speedup 1.0000x reference)
//
#include <hip/hip_runtime.h>
#include <math.h>

#define B_ 2
#define T_ 128
#define F_ 88
#define HID 64
#define NU 64
#define NH 4
#define HD 16
#define LH 32
#define NSEQ (B_*F_)
#define NTOK (B_*T_*F_)
#define NPOS (T_*F_)

__device__ __forceinline__ float sigf(float x) { return 1.0f/(1.0f + expf(-x)); }

// ---------------------------------------------------------------------------
// BiLSTM layer: 1 block per sequence, 256 threads = 2 dirs x 128 gate rows.
// Weights per thread in registers; x sequence staged in LDS; h broadcast via LDS.
// ---------------------------------------------------------------------------
template<int LAYER>
__global__ void __launch_bounds__(256) lstm_kernel(
    const float* __restrict__ xin,   // L0: x (B,T*F,64); L1: h0 (NSEQ,T,64)
    const float* __restrict__ w_ih,  // (2,2,128,64)
    const float* __restrict__ w_hh,  // (2,2,128,32)
    const float* __restrict__ b_ih,  // (2,2,128)
    const float* __restrict__ b_hh,  // (2,2,128)
    float* __restrict__ outp)        // L0: h0 (NSEQ,T,64); L1: hcur (B,T,F,64)
{
    __shared__ float xs[T_][HID];
    __shared__ float hsh[2][LH];
    __shared__ float gsh[2][4*LH];
    const int s = blockIdx.x;
    const int b = s / F_, f = s % F_;
    const int tid = threadIdx.x;
    const int dir = tid >> 7;
    const int j = tid & 127;

    // stage input sequence (32KB), coalesced
    for (int n = tid; n < T_*HID; n += 256) {
        const int tt = n >> 6, k = n & 63;
        xs[tt][k] = (LAYER == 0) ? xin[((b*T_ + tt)*F_ + f)*HID + k]
                                 : xin[(s*T_ + tt)*HID + k];
    }

    // per-thread weight rows in registers
    const int wrow = (LAYER*2 + dir)*128 + j;
    float wih[HID];
    {
        const float4* wp = (const float4*)(w_ih + (size_t)wrow*HID);
        #pragma unroll
        for (int k4 = 0; k4 < HID/4; k4++) {
            float4 v = wp[k4];
            wih[k4*4+0]=v.x; wih[k4*4+1]=v.y; wih[k4*4+2]=v.z; wih[k4*4+3]=v.w;
        }
    }
    float whh[LH];
    {
        const float4* wp = (const float4*)(w_hh + (size_t)wrow*LH);
        #pragma unroll
        for (int k4 = 0; k4 < LH/4; k4++) {
            float4 v = wp[k4];
            whh[k4*4+0]=v.x; whh[k4*4+1]=v.y; whh[k4*4+2]=v.z; whh[k4*4+3]=v.w;
        }
    }
    const float bias = b_ih[wrow] + b_hh[wrow];

    float c = 0.f;
    if (j < LH) hsh[dir][j] = 0.f;
    __syncthreads();

    for (int step = 0; step < T_; step++) {
        const int time = dir ? (T_-1-step) : step;
        float g = bias;
        const float* xt = xs[time];
        #pragma unroll
        for (int k = 0; k < HID; k++) g += wih[k]*xt[k];
        #pragma unroll
        for (int k = 0; k < LH; k++) g += whh[k]*hsh[dir][k];
        gsh[dir][j] = g;
        __syncthreads();
        if (j < LH) {
            const float gi = gsh[dir][j];
            const float gf = gsh[dir][LH+j];
            const float gg = gsh[dir][2*LH+j];
            const float go = gsh[dir][3*LH+j];
            c = sigf(gf)*c + sigf(gi)*tanhf(gg);
            const float h = sigf(go)*tanhf(c);
            hsh[dir][j] = h;
            if (LAYER == 0)
                outp[((size_t)s*T_ + time)*NU + dir*LH + j] = h;
            else
                outp[(((size_t)b*T_ + time)*F_ + f)*NU + dir*LH + j] = h;
        }
        __syncthreads();
    }
}

// ---------------------------------------------------------------------------
// qkv: per block computes a 64-token x 64-col slice (which = q/k/v) of
// (h + emb[t[b]]) @ Wqkv + b.  Writes split q/k/v buffers in (b,h,pos,d).
// ---------------------------------------------------------------------------
__global__ void __launch_bounds__(256) qkv_kernel(
    const float* __restrict__ hcur,  // (NTOK,64)
    const int*   __restrict__ tarr,  // (B)
    const float* __restrict__ t_emb, // (2,100,64)
    const float* __restrict__ w_qkv, // (2,64,192)
    const float* __restrict__ b_qkv, // (2,192)
    const int layer,
    float* __restrict__ qb, float* __restrict__ kb, float* __restrict__ vb)
{
    __shared__ float as[64][65];
    __shared__ float wsh[64][64];
    const int m0 = blockIdx.x * 64;
    const int which = blockIdx.y;
    const int tid = threadIdx.x;
    const int bidx = m0 / NPOS;
    const int tb = tarr[bidx];
    const float* embp = t_emb + ((size_t)layer*100 + tb)*HID;

    for (int n = tid; n < 64*64; n += 256) {
        const int mm = n >> 6, k = n & 63;
        as[mm][k]  = hcur[((size_t)m0+mm)*64 + k] + embp[k];
        wsh[mm][k] = w_qkv[((size_t)layer*64 + mm)*192 + which*64 + k];
    }
    __syncthreads();

    const int tm = tid >> 4, tn = tid & 15;
    float acc[4][4] = {};
    for (int k = 0; k < 64; k++) {
        const float a0 = as[tm*4+0][k];
        const float a1 = as[tm*4+1][k];
        const float a2 = as[tm*4+2][k];
        const float a3 = as[tm*4+3][k];
        const float4 w = *(const float4*)&wsh[k][tn*4];
        acc[0][0]+=a0*w.x; acc[0][1]+=a0*w.y; acc[0][2]+=a0*w.z; acc[0][3]+=a0*w.w;
        acc[1][0]+=a1*w.x; acc[1][1]+=a1*w.y; acc[1][2]+=a1*w.z; acc[1][3]+=a1*w.w;
        acc[2][0]+=a2*w.x; acc[2][1]+=a2*w.y; acc[2][2]+=a2*w.z; acc[2][3]+=a2*w.w;
        acc[3][0]+=a3*w.x; acc[3][1]+=a3*w.y; acc[3][2]+=a3*w.z; acc[3][3]+=a3*w.w;
    }

    float* dst = (which == 0) ? qb : (which == 1) ? kb : vb;
    const float scale = (which == 0) ? 0.25f : 1.0f;   // HEAD_DIM^-0.5
    const int hh = tn >> 2;
    const int dbase = (tn & 3) * 4;
    const float4 bv = *(const float4*)&b_qkv[(size_t)layer*192 + which*64 + tn*4];
    #pragma unroll
    for (int r = 0; r < 4; r++) {
        const int row = m0 + tm*4 + r;
        const int pos = row - bidx*NPOS;
        float4 o;
        o.x = (acc[r][0] + bv.x) * scale;
        o.y = (acc[r][1] + bv.y) * scale;
        o.z = (acc[r][2] + bv.z) * scale;
        o.w = (acc[r][3] + bv.w) * scale;
        *(float4*)&dst[(((size_t)bidx*NH + hh)*NPOS + pos)*HD + dbase] = o;
    }
}

// ---------------------------------------------------------------------------
// Neighborhood attention: block per (b,h,i). Stage 7 k-rows in LDS (pad 20),
// 49 logits + bias + softmax in registers, restage v, weighted sum.
// ---------------------------------------------------------------------------
__global__ void __launch_bounds__(128) nattn_kernel(
    const float* __restrict__ qb,
    const float* __restrict__ kb,
    const float* __restrict__ vb,
    const float* __restrict__ rpb,   // (2,4,13,13)
    const int layer,
    float* __restrict__ ao)          // (B,T,F,64)
{
    __shared__ float ks[7][88][20];
    __shared__ float rp[169];
    const int blk = blockIdx.x;
    const int i  = blk & 127;
    const int bh = blk >> 7;        // b*4+h
    const int h  = bh & 3;
    const int bb = bh >> 2;
    const int tid = threadIdx.x;
    const int ihs = min(max(i-3, 0), T_-7);
    const float* kbase = kb + (size_t)bh*NPOS*HD;
    const float* vbase = vb + (size_t)bh*NPOS*HD;

    for (int n = tid; n < 169; n += 128)          // FIX: 128 threads, 169 entries
        rp[n] = rpb[((size_t)layer*NH + h)*169 + n];
    for (int n4 = tid; n4 < 7*88*4; n4 += 128) {
        const int d4 = n4 & 3;
        const int c  = (n4 >> 2) % 88;
        const int ki = n4 / 352;
        *(float4*)&ks[ki][c][d4*4] =
            *(const float4*)&kbase[((size_t)(ihs+ki)*F_ + c)*HD + d4*4];
    }
    __syncthreads();

    const int j = tid;
    const bool act = (j < F_);
    float lg[49];
    int cw = 0;
    if (act) {
        cw = min(max(j-3, 0), F_-7);
        const float4* qp = (const float4*)&qb[((size_t)bh*NPOS + i*F_ + j)*HD];
        const float4 q0 = qp[0], q1 = qp[1], q2 = qp[2], q3 = qp[3];
        #pragma unroll
        for (int ki = 0; ki < 7; ki++) {
            const int rh = ihs + ki - i + 6;
            #pragma unroll
            for (int kj = 0; kj < 7; kj++) {
                const float4* kp = (const float4*)&ks[ki][cw+kj][0];
                const float4 k0 = kp[0], k1 = kp[1], k2 = kp[2], k3 = kp[3];
                float d = q0.x*k0.x + q0.y*k0.y + q0.z*k0.z + q0.w*k0.w
                        + q1.x*k1.x + q1.y*k1.y + q1.z*k1.z + q1.w*k1.w
                        + q2.x*k2.x + q2.y*k2.y + q2.z*k2.z + q2.w*k2.w
                        + q3.x*k3.x + q3.y*k3.y + q3.z*k3.z + q3.w*k3.w;
                lg[ki*7+kj] = d + rp[rh*13 + (cw + kj - j + 6)];
            }
        }
        float m = lg[0];
        #pragma unroll
        for (int n = 1; n < 49; n++) m = fmaxf(m, lg[n]);
        float ssum = 0.f;
        #pragma unroll
        for (int n = 0; n < 49; n++) { lg[n] = __expf(lg[n] - m); ssum += lg[n]; }
        const float inv = 1.f/ssum;
        #pragma unroll
        for (int n = 0; n < 49; n++) lg[n] *= inv;
    }
    __syncthreads();
    // restage v over same LDS
    for (int n4 = tid; n4 < 7*88*4; n4 += 128) {
        const int d4 = n4 & 3;
        const int c  = (n4 >> 2) % 88;
        const int ki = n4 / 352;
        *(float4*)&ks[ki][c][d4*4] =
            *(const float4*)&vbase[((size_t)(ihs+ki)*F_ + c)*HD + d4*4];
    }
    __syncthreads();
    if (act) {
        float4 o0 = {0,0,0,0}, o1 = {0,0,0,0}, o2 = {0,0,0,0}, o3 = {0,0,0,0};
        #pragma unroll
        for (int ki = 0; ki < 7; ki++) {
            #pragma unroll
            for (int kj = 0; kj < 7; kj++) {
                const float a = lg[ki*7+kj];
                const float4* vp = (const float4*)&ks[ki][cw+kj][0];
                const float4 v0 = vp[0], v1 = vp[1], v2 = vp[2], v3 = vp[3];
                o0.x += a*v0.x; o0.y += a*v0.y; o0.z += a*v0.z; o0.w += a*v0.w;
                o1.x += a*v1.x; o1.y += a*v1.y; o1.z += a*v1.z; o1.w += a*v1.w;
                o2.x += a*v2.x; o2.y += a*v2.y; o2.z += a*v2.z; o2.w += a*v2.w;
                o3.x += a*v3.x; o3.y += a*v3.y; o3.z += a*v3.z; o3.w += a*v3.w;
            }
        }
        float4* op = (float4*)&ao[(((size_t)bb*T_ + i)*F_ + j)*NU + h*HD];
        op[0]=o0; op[1]=o1; op[2]=o2; op[3]=o3;
    }
}

// ---------------------------------------------------------------------------
// proj + residual: out = hres + ain @ Wproj + b
// ---------------------------------------------------------------------------
__global__ void __launch_bounds__(256) proj_kernel(
    const float* __restrict__ ain,   // (NTOK,64)
    const float* __restrict__ hres,  // (NTOK,64)
    const float* __restrict__ w_proj,// (2,64,64)
    const float* __restrict__ b_proj,// (2,64)
    const int layer,
    float* __restrict__ outp)
{
    __shared__ float as[64][65];
    __shared__ float wsh[64][64];
    const int m0 = blockIdx.x * 64;
    const int tid = threadIdx.x;
    for (int n = tid; n < 64*64; n += 256) {
        const int mm = n >> 6, k = n & 63;
        as[mm][k]  = ain[((size_t)m0+mm)*64 + k];
        wsh[mm][k] = w_proj[(size_t)layer*4096 + n];
    }
    __syncthreads();
    const int tm = tid >> 4, tn = tid & 15;
    float acc[4][4] = {};
    for (int k = 0; k < 64; k++) {
        const float a0 = as[tm*4+0][k];
        const float a1 = as[tm*4+1][k];
        const float a2 = as[tm*4+2][k];
        const float a3 = as[tm*4+3][k];
        const float4 w = *(const float4*)&wsh[k][tn*4];
        acc[0][0]+=a0*w.x; acc[0][1]+=a0*w.y; acc[0][2]+=a0*w.z; acc[0][3]+=a0*w.w;
        acc[1][0]+=a1*w.x; acc[1][1]+=a1*w.y; acc[1][2]+=a1*w.z; acc[1][3]+=a1*w.w;
        acc[2][0]+=a2*w.x; acc[2][1]+=a2*w.y; acc[2][2]+=a2*w.z; acc[2][3]+=a2*w.w;
        acc[3][0]+=a3*w.x; acc[3][1]+=a3*w.y; acc[3][2]+=a3*w.z; acc[3][3]+=a3*w.w;
    }
    const float4 bv = *(const float4*)&b_proj[(size_t)layer*64 + tn*4];
    #pragma unroll
    for (int r = 0; r < 4; r++) {
        const int row = m0 + tm*4 + r;
        const float4 hv = *(const float4*)&hres[(size_t)row*64 + tn*4];
        float4 o;
        o.x = hv.x + acc[r][0] + bv.x;
        o.y = hv.y + acc[r][1] + bv.y;
        o.z = hv.z + acc[r][2] + bv.z;
        o.w = hv.w + acc[r][3] + bv.w;
        *(float4*)&outp[(size_t)row*64 + tn*4] = o;
    }
}

extern "C" void kernel_launch(void* const* d_in, const int* in_sizes, int n_in,
                              void* d_out, int out_size, void* d_ws, size_t ws_size,
                              hipStream_t stream) {
    const float* x      = (const float*)d_in[0];
    const int*   tarr   = (const int*)  d_in[1];
    const float* w_ih   = (const float*)d_in[2];
    const float* w_hh   = (const float*)d_in[3];
    const float* b_ih   = (const float*)d_in[4];
    const float* b_hh   = (const float*)d_in[5];
    const float* t_emb  = (const float*)d_in[6];
    const float* w_qkv  = (const float*)d_in[7];
    const float* b_qkv  = (const float*)d_in[8];
    const float* rpb    = (const float*)d_in[9];
    const float* w_proj = (const float*)d_in[10];
    const float* b_proj = (const float*)d_in[11];

    float* ws   = (float*)d_ws;
    const size_t CH = (size_t)NTOK * NU;   // 1441792 floats
    float* hcur = ws;
    float* h0   = ws + CH;
    float* qbuf = ws + 2*CH;
    float* kbuf = ws + 3*CH;
    float* vbuf = ws + 4*CH;
    float* ao   = ws + 5*CH;
    float* outp = (float*)d_out;

    lstm_kernel<0><<<NSEQ, 256, 0, stream>>>(x,  w_ih, w_hh, b_ih, b_hh, h0);
    lstm_kernel<1><<<NSEQ, 256, 0, stream>>>(h0, w_ih, w_hh, b_ih, b_hh, hcur);

    for (int l = 0; l < 2; l++) {
        qkv_kernel<<<dim3(NTOK/64, 3), 256, 0, stream>>>(
            hcur, tarr, t_emb, w_qkv, b_qkv, l, qbuf, kbuf, vbuf);
        nattn_kernel<<<B_*NH*T_, 128, 0, stream>>>(
            qbuf, kbuf, vbuf, rpb, l, ao);
        proj_kernel<<<NTOK/64, 256, 0, stream>>>(
            ao, hcur, w_proj, b_proj, l, (l == 0) ? hcur : outp);
    }
}

// Round 3
// 304.757 us; speedup vs baseline: 1.2681x; 1.2681x over previous
//
#include <hip/hip_runtime.h>
#include <math.h>

#define B_ 2
#define T_ 128
#define F_ 88
#define HID 64
#define NU 64
#define NH 4
#define HD 16
#define LH 32
#define NSEQ (B_*F_)
#define NTOK (B_*T_*F_)
#define NPOS (T_*F_)

__device__ __forceinline__ float fexp(float x) { return __expf(x); }
__device__ __forceinline__ float fsig(float x) {
    return __builtin_amdgcn_rcpf(1.0f + __expf(-x));
}
__device__ __forceinline__ float ftanh(float x) {
    // tanh(x) = 2*sigmoid(2x) - 1
    return 2.0f * __builtin_amdgcn_rcpf(1.0f + __expf(-2.0f*x)) - 1.0f;
}
__device__ __forceinline__ float rdlane(float v, int l) {
    return __uint_as_float(__builtin_amdgcn_readlane(__float_as_uint(v), l));
}

// ---------------------------------------------------------------------------
// Gate pre-activation GEMM: G[s][dir][t][row] = x_t . W_ih[row] + (b_ih+b_hh)
// Block = (seq, 32-timestep chunk); 256 threads; both dirs (256 rows).
// ---------------------------------------------------------------------------
template<int LAYER>
__global__ void __launch_bounds__(256, 2) gg_kernel(
    const float* __restrict__ xin,   // L0: x (B,T,F,64); L1: h0 (NSEQ,T,64)
    const float* __restrict__ w_ih,  // (2,2,128,64)
    const float* __restrict__ b_ih,  // (2,2,128)
    const float* __restrict__ b_hh,  // (2,2,128)
    float* __restrict__ G)           // (NSEQ,2,T,128)
{
    __shared__ float xts[32][65];
    __shared__ float wsh[256][65];
    __shared__ float bsh[256];
    const int s  = blockIdx.x;
    const int t0 = blockIdx.y * 32;
    const int b = s / F_, f = s % F_;
    const int tid = threadIdx.x;

    for (int n = tid; n < 32*64; n += 256) {
        const int tt = n >> 6, k = n & 63;
        xts[tt][k] = (LAYER == 0)
            ? xin[(((size_t)b*T_ + t0+tt)*F_ + f)*HID + k]
            : xin[((size_t)s*T_ + t0+tt)*HID + k];
    }
    for (int n = tid; n < 256*64; n += 256) {
        const int row = n >> 6, k = n & 63;
        wsh[row][k] = w_ih[((size_t)LAYER*256 + row)*HID + k];
    }
    if (tid < 256)
        bsh[tid] = b_ih[LAYER*256 + tid] + b_hh[LAYER*256 + tid];
    __syncthreads();

    const int tr = tid >> 3;   // 0..31 -> rows tr*8..tr*8+7
    const int tc = tid & 7;    // 0..7  -> ts  tc*4..tc*4+3
    float acc[8][4] = {};
    #pragma unroll 4
    for (int k = 0; k < 64; k++) {
        float xv[4];
        #pragma unroll
        for (int i = 0; i < 4; i++) xv[i] = xts[tc*4+i][k];
        #pragma unroll
        for (int r = 0; r < 8; r++) {
            const float wv = wsh[tr*8+r][k];
            #pragma unroll
            for (int i = 0; i < 4; i++) acc[r][i] += wv * xv[i];
        }
    }
    #pragma unroll
    for (int r = 0; r < 8; r++) {
        const int row = tr*8 + r;
        const int dir = row >> 7, rr = row & 127;
        const float bb = bsh[row];
        #pragma unroll
        for (int i = 0; i < 4; i++) {
            const int t = t0 + tc*4 + i;
            G[(((size_t)s*2 + dir)*T_ + t)*128 + rr] = acc[r][i] + bb;
        }
    }
}

// ---------------------------------------------------------------------------
// LSTM recurrence (gates precomputed). Block = seq, 128 thr = 2 waves (dirs).
// Lane l owns gate rows l and 64+l. h broadcast via readlane; no LDS/barriers.
// ---------------------------------------------------------------------------
template<int LAYER>
__global__ void __launch_bounds__(128, 1) lstm_rec(
    const float* __restrict__ G,     // (NSEQ,2,T,128)
    const float* __restrict__ w_hh,  // (2,2,128,32)
    float* __restrict__ outp)        // L0: (NSEQ,T,64); L1: (B,T,F,64)
{
    const int s = blockIdx.x;
    const int b = s / F_, f = s % F_;
    const int lane = threadIdx.x & 63;
    const int dir  = threadIdx.x >> 6;

    float whA[LH], whB[LH];
    {
        const float4* pa = (const float4*)(w_hh + ((size_t)(LAYER*2+dir)*128 + lane)*LH);
        const float4* pb = (const float4*)(w_hh + ((size_t)(LAYER*2+dir)*128 + 64 + lane)*LH);
        #pragma unroll
        for (int k4 = 0; k4 < LH/4; k4++) {
            float4 a = pa[k4], c = pb[k4];
            whA[k4*4+0]=a.x; whA[k4*4+1]=a.y; whA[k4*4+2]=a.z; whA[k4*4+3]=a.w;
            whB[k4*4+0]=c.x; whB[k4*4+1]=c.y; whB[k4*4+2]=c.z; whB[k4*4+3]=c.w;
        }
    }
    const float* gseq = G + ((size_t)(s*2 + dir)*T_)*128;
    #define GTIME(st) (dir ? (T_-1-(st)) : (st))

    float h = 0.f, c = 0.f;
    // prefetch steps 0 and 1
    float a0A = gseq[GTIME(0)*128 + lane];
    float a0B = gseq[GTIME(0)*128 + 64 + lane];
    float a1A = gseq[GTIME(1)*128 + lane];
    float a1B = gseq[GTIME(1)*128 + 64 + lane];

    #define STEP(gAv, gBv, stepi)                                            \
    {                                                                        \
        float accA = (gAv), accB = (gBv);                                    \
        _Pragma("unroll")                                                    \
        for (int k = 0; k < LH; k++) {                                       \
            const float hk = rdlane(h, k);                                   \
            accA += whA[k]*hk; accB += whB[k]*hk;                            \
        }                                                                    \
        const float e0 = fsig(accA);                                         \
        const float e1 = (lane < LH) ? ftanh(accB) : fsig(accB);             \
        const float x0 = __shfl_xor(e0, 32, 64);  /* lanes<32: sig(f) */     \
        const float x1 = __shfl_xor(e1, 32, 64);  /* lanes<32: sig(o) */     \
        c = x0*c + e0*e1;                                                    \
        h = x1 * ftanh(c);                                                   \
        if (lane < LH) {                                                     \
            const int tm = GTIME(stepi);                                     \
            if (LAYER == 0)                                                  \
                outp[((size_t)s*T_ + tm)*NU + dir*LH + lane] = h;            \
            else                                                             \
                outp[(((size_t)b*T_ + tm)*F_ + f)*NU + dir*LH + lane] = h;   \
        }                                                                    \
    }

    for (int s2 = 0; s2 < T_; s2 += 2) {
        const int p0 = min(s2+2, T_-1);
        const float n0A = gseq[GTIME(p0)*128 + lane];
        const float n0B = gseq[GTIME(p0)*128 + 64 + lane];
        STEP(a0A, a0B, s2);
        const int p1 = min(s2+3, T_-1);
        const float n1A = gseq[GTIME(p1)*128 + lane];
        const float n1B = gseq[GTIME(p1)*128 + 64 + lane];
        STEP(a1A, a1B, s2+1);
        a0A = n0A; a0B = n0B; a1A = n1A; a1B = n1B;
    }
    #undef STEP
    #undef GTIME
}

// ---------------------------------------------------------------------------
// qkv: per block computes a 64-token x 64-col slice (which = q/k/v) of
// (h + emb[t[b]]) @ Wqkv + b.  Writes split q/k/v buffers in (b,h,pos,d).
// ---------------------------------------------------------------------------
__global__ void __launch_bounds__(256, 2) qkv_kernel(
    const float* __restrict__ hcur,  // (NTOK,64)
    const int*   __restrict__ tarr,  // (B)
    const float* __restrict__ t_emb, // (2,100,64)
    const float* __restrict__ w_qkv, // (2,64,192)
    const float* __restrict__ b_qkv, // (2,192)
    const int layer,
    float* __restrict__ qb, float* __restrict__ kb, float* __restrict__ vb)
{
    __shared__ float as[64][65];
    __shared__ float wsh[64][64];
    const int m0 = blockIdx.x * 64;
    const int which = blockIdx.y;
    const int tid = threadIdx.x;
    const int bidx = m0 / NPOS;
    const int tb = tarr[bidx];
    const float* embp = t_emb + ((size_t)layer*100 + tb)*HID;

    for (int n = tid; n < 64*64; n += 256) {
        const int mm = n >> 6, k = n & 63;
        as[mm][k]  = hcur[((size_t)m0+mm)*64 + k] + embp[k];
        wsh[mm][k] = w_qkv[((size_t)layer*64 + mm)*192 + which*64 + k];
    }
    __syncthreads();

    const int tm = tid >> 4, tn = tid & 15;
    float acc[4][4] = {};
    for (int k = 0; k < 64; k++) {
        const float a0 = as[tm*4+0][k];
        const float a1 = as[tm*4+1][k];
        const float a2 = as[tm*4+2][k];
        const float a3 = as[tm*4+3][k];
        const float4 w = *(const float4*)&wsh[k][tn*4];
        acc[0][0]+=a0*w.x; acc[0][1]+=a0*w.y; acc[0][2]+=a0*w.z; acc[0][3]+=a0*w.w;
        acc[1][0]+=a1*w.x; acc[1][1]+=a1*w.y; acc[1][2]+=a1*w.z; acc[1][3]+=a1*w.w;
        acc[2][0]+=a2*w.x; acc[2][1]+=a2*w.y; acc[2][2]+=a2*w.z; acc[2][3]+=a2*w.w;
        acc[3][0]+=a3*w.x; acc[3][1]+=a3*w.y; acc[3][2]+=a3*w.z; acc[3][3]+=a3*w.w;
    }

    float* dst = (which == 0) ? qb : (which == 1) ? kb : vb;
    const float scale = (which == 0) ? 0.25f : 1.0f;   // HEAD_DIM^-0.5
    const int hh = tn >> 2;
    const int dbase = (tn & 3) * 4;
    const float4 bv = *(const float4*)&b_qkv[(size_t)layer*192 + which*64 + tn*4];
    #pragma unroll
    for (int r = 0; r < 4; r++) {
        const int row = m0 + tm*4 + r;
        const int pos = row - bidx*NPOS;
        float4 o;
        o.x = (acc[r][0] + bv.x) * scale;
        o.y = (acc[r][1] + bv.y) * scale;
        o.z = (acc[r][2] + bv.z) * scale;
        o.w = (acc[r][3] + bv.w) * scale;
        *(float4*)&dst[(((size_t)bidx*NH + hh)*NPOS + pos)*HD + dbase] = o;
    }
}

// ---------------------------------------------------------------------------
// Neighborhood attention: block per (b,h,i). Stage 7 k-rows in LDS (pad 20),
// 49 logits + bias + softmax in registers, restage v, weighted sum.
// ---------------------------------------------------------------------------
__global__ void __launch_bounds__(128, 2) nattn_kernel(
    const float* __restrict__ qb,
    const float* __restrict__ kb,
    const float* __restrict__ vb,
    const float* __restrict__ rpb,   // (2,4,13,13)
    const int layer,
    float* __restrict__ ao)          // (B,T,F,64)
{
    __shared__ float ks[7][88][20];
    __shared__ float rp[169];
    const int blk = blockIdx.x;
    const int i  = blk & 127;
    const int bh = blk >> 7;        // b*4+h
    const int h  = bh & 3;
    const int bb = bh >> 2;
    const int tid = threadIdx.x;
    const int ihs = min(max(i-3, 0), T_-7);
    const float* kbase = kb + (size_t)bh*NPOS*HD;
    const float* vbase = vb + (size_t)bh*NPOS*HD;

    for (int n = tid; n < 169; n += 128)
        rp[n] = rpb[((size_t)layer*NH + h)*169 + n];
    for (int n4 = tid; n4 < 7*88*4; n4 += 128) {
        const int d4 = n4 & 3;
        const int c  = (n4 >> 2) % 88;
        const int ki = n4 / 352;
        *(float4*)&ks[ki][c][d4*4] =
            *(const float4*)&kbase[((size_t)(ihs+ki)*F_ + c)*HD + d4*4];
    }
    __syncthreads();

    const int j = tid;
    const bool act = (j < F_);
    float lg[49];
    int cw = 0;
    if (act) {
        cw = min(max(j-3, 0), F_-7);
        const float4* qp = (const float4*)&qb[((size_t)bh*NPOS + i*F_ + j)*HD];
        const float4 q0 = qp[0], q1 = qp[1], q2 = qp[2], q3 = qp[3];
        #pragma unroll
        for (int ki = 0; ki < 7; ki++) {
            const int rh = ihs + ki - i + 6;
            #pragma unroll
            for (int kj = 0; kj < 7; kj++) {
                const float4* kp = (const float4*)&ks[ki][cw+kj][0];
                const float4 k0 = kp[0], k1 = kp[1], k2 = kp[2], k3 = kp[3];
                float d = q0.x*k0.x + q0.y*k0.y + q0.z*k0.z + q0.w*k0.w
                        + q1.x*k1.x + q1.y*k1.y + q1.z*k1.z + q1.w*k1.w
                        + q2.x*k2.x + q2.y*k2.y + q2.z*k2.z + q2.w*k2.w
                        + q3.x*k3.x + q3.y*k3.y + q3.z*k3.z + q3.w*k3.w;
                lg[ki*7+kj] = d + rp[rh*13 + (cw + kj - j + 6)];
            }
        }
        float m = lg[0];
        #pragma unroll
        for (int n = 1; n < 49; n++) m = fmaxf(m, lg[n]);
        float ssum = 0.f;
        #pragma unroll
        for (int n = 0; n < 49; n++) { lg[n] = __expf(lg[n] - m); ssum += lg[n]; }
        const float inv = __builtin_amdgcn_rcpf(ssum);
        #pragma unroll
        for (int n = 0; n < 49; n++) lg[n] *= inv;
    }
    __syncthreads();
    for (int n4 = tid; n4 < 7*88*4; n4 += 128) {
        const int d4 = n4 & 3;
        const int c  = (n4 >> 2) % 88;
        const int ki = n4 / 352;
        *(float4*)&ks[ki][c][d4*4] =
            *(const float4*)&vbase[((size_t)(ihs+ki)*F_ + c)*HD + d4*4];
    }
    __syncthreads();
    if (act) {
        float4 o0 = {0,0,0,0}, o1 = {0,0,0,0}, o2 = {0,0,0,0}, o3 = {0,0,0,0};
        #pragma unroll
        for (int ki = 0; ki < 7; ki++) {
            #pragma unroll
            for (int kj = 0; kj < 7; kj++) {
                const float a = lg[ki*7+kj];
                const float4* vp = (const float4*)&ks[ki][cw+kj][0];
                const float4 v0 = vp[0], v1 = vp[1], v2 = vp[2], v3 = vp[3];
                o0.x += a*v0.x; o0.y += a*v0.y; o0.z += a*v0.z; o0.w += a*v0.w;
                o1.x += a*v1.x; o1.y += a*v1.y; o1.z += a*v1.z; o1.w += a*v1.w;
                o2.x += a*v2.x; o2.y += a*v2.y; o2.z += a*v2.z; o2.w += a*v2.w;
                o3.x += a*v3.x; o3.y += a*v3.y; o3.z += a*v3.z; o3.w += a*v3.w;
            }
        }
        float4* op = (float4*)&ao[(((size_t)bb*T_ + i)*F_ + j)*NU + h*HD];
        op[0]=o0; op[1]=o1; op[2]=o2; op[3]=o3;
    }
}

// ---------------------------------------------------------------------------
// proj + residual: out = hres + ain @ Wproj + b
// ---------------------------------------------------------------------------
__global__ void __launch_bounds__(256, 2) proj_kernel(
    const float* __restrict__ ain,   // (NTOK,64)
    const float* __restrict__ hres,  // (NTOK,64)
    const float* __restrict__ w_proj,// (2,64,64)
    const float* __restrict__ b_proj,// (2,64)
    const int layer,
    float* __restrict__ outp)
{
    __shared__ float as[64][65];
    __shared__ float wsh[64][64];
    const int m0 = blockIdx.x * 64;
    const int tid = threadIdx.x;
    for (int n = tid; n < 64*64; n += 256) {
        const int mm = n >> 6, k = n & 63;
        as[mm][k]  = ain[((size_t)m0+mm)*64 + k];
        wsh[mm][k] = w_proj[(size_t)layer*4096 + n];
    }
    __syncthreads();
    const int tm = tid >> 4, tn = tid & 15;
    float acc[4][4] = {};
    for (int k = 0; k < 64; k++) {
        const float a0 = as[tm*4+0][k];
        const float a1 = as[tm*4+1][k];
        const float a2 = as[tm*4+2][k];
        const float a3 = as[tm*4+3][k];
        const float4 w = *(const float4*)&wsh[k][tn*4];
        acc[0][0]+=a0*w.x; acc[0][1]+=a0*w.y; acc[0][2]+=a0*w.z; acc[0][3]+=a0*w.w;
        acc[1][0]+=a1*w.x; acc[1][1]+=a1*w.y; acc[1][2]+=a1*w.z; acc[1][3]+=a1*w.w;
        acc[2][0]+=a2*w.x; acc[2][1]+=a2*w.y; acc[2][2]+=a2*w.z; acc[2][3]+=a2*w.w;
        acc[3][0]+=a3*w.x; acc[3][1]+=a3*w.y; acc[3][2]+=a3*w.z; acc[3][3]+=a3*w.w;
    }
    const float4 bv = *(const float4*)&b_proj[(size_t)layer*64 + tn*4];
    #pragma unroll
    for (int r = 0; r < 4; r++) {
        const int row = m0 + tm*4 + r;
        const float4 hv = *(const float4*)&hres[(size_t)row*64 + tn*4];
        float4 o;
        o.x = hv.x + acc[r][0] + bv.x;
        o.y = hv.y + acc[r][1] + bv.y;
        o.z = hv.z + acc[r][2] + bv.z;
        o.w = hv.w + acc[r][3] + bv.w;
        *(float4*)&outp[(size_t)row*64 + tn*4] = o;
    }
}

extern "C" void kernel_launch(void* const* d_in, const int* in_sizes, int n_in,
                              void* d_out, int out_size, void* d_ws, size_t ws_size,
                              hipStream_t stream) {
    const float* x      = (const float*)d_in[0];
    const int*   tarr   = (const int*)  d_in[1];
    const float* w_ih   = (const float*)d_in[2];
    const float* w_hh   = (const float*)d_in[3];
    const float* b_ih   = (const float*)d_in[4];
    const float* b_hh   = (const float*)d_in[5];
    const float* t_emb  = (const float*)d_in[6];
    const float* w_qkv  = (const float*)d_in[7];
    const float* b_qkv  = (const float*)d_in[8];
    const float* rpb    = (const float*)d_in[9];
    const float* w_proj = (const float*)d_in[10];
    const float* b_proj = (const float*)d_in[11];

    float* ws   = (float*)d_ws;
    const size_t CH = (size_t)NTOK * NU;   // 1441792 floats
    float* hcur = ws;                      // (B,T,F,64)
    float* h0   = ws + CH;                 // (NSEQ,T,64)
    float* G    = ws + 2*CH;               // (NSEQ,2,T,128) == 4*CH floats, dead after LSTM
    float* qbuf = ws + 2*CH;               // overlays G after LSTM phase
    float* kbuf = ws + 3*CH;
    float* vbuf = ws + 4*CH;
    float* ao   = ws + 5*CH;
    float* outp = (float*)d_out;

    gg_kernel<0><<<dim3(NSEQ, T_/32), 256, 0, stream>>>(x,  w_ih, b_ih, b_hh, G);
    lstm_rec<0><<<NSEQ, 128, 0, stream>>>(G, w_hh, h0);
    gg_kernel<1><<<dim3(NSEQ, T_/32), 256, 0, stream>>>(h0, w_ih, b_ih, b_hh, G);
    lstm_rec<1><<<NSEQ, 128, 0, stream>>>(G, w_hh, hcur);

    for (int l = 0; l < 2; l++) {
        qkv_kernel<<<dim3(NTOK/64, 3), 256, 0, stream>>>(
            hcur, tarr, t_emb, w_qkv, b_qkv, l, qbuf, kbuf, vbuf);
        nattn_kernel<<<B_*NH*T_, 128, 0, stream>>>(
            qbuf, kbuf, vbuf, rpb, l, ao);
        proj_kernel<<<NTOK/64, 256, 0, stream>>>(
            ao, hcur, w_proj, b_proj, l, (l == 0) ? hcur : outp);
    }
}